// Round 3
// baseline (25866.052 us; speedup 1.0000x reference)
//
#include <hip/hip_runtime.h>
#include <hip/hip_bf16.h>
#include <hip/hip_cooperative_groups.h>

namespace cg = cooperative_groups;

#define UNITS 1024
#define FEAT  16
#define TSTEPS 512
#define OUTSTEPS 24
#define BATCH 256
#define KTOT  1088   // 16 (x) + 1024 (h) + 48 pad
#define NROWS 4096   // 4*UNITS, reordered r = 4*u + gate

typedef __bf16 bf16x8 __attribute__((ext_vector_type(8)));
typedef float  f32x4  __attribute__((ext_vector_type(4)));

__device__ __forceinline__ float sigmoidf_(float x) { return 1.f / (1.f + __expf(-x)); }
__device__ __forceinline__ float tanhf_(float x)    { return 1.f - 2.f / (__expf(2.f * x) + 1.f); }

// quad_perm broadcast: take value from lane (lane&~3)+SEL, SEL encoded 4x
template <int CTRL>
__device__ __forceinline__ float qb(float v) {
    int i = __builtin_amdgcn_mov_dpp(__float_as_int(v), CTRL, 0xF, 0xF, false);
    return __int_as_float(i);
}

// ---------------------------------------------------------------------------
// Build Wcat_T[r][k] (bf16, row-major, stride KTOT), r = 4*u + g -> orig col
// c = g*1024 + u.  k<16: kernel[k][c]; 16<=k<1040: rec_kernel[k-16][c]; else 0.
// ---------------------------------------------------------------------------
__global__ __launch_bounds__(256) void prep_weights(const float* __restrict__ kern,
                                                    const float* __restrict__ rec,
                                                    __bf16* __restrict__ Wcat) {
    __shared__ __align__(16) __bf16 tile[64][72];
    int r0 = blockIdx.x * 64;
    int k0 = blockIdx.y * 64;
    int t  = threadIdx.x;
    int c_off = t & 63;
    int k_grp = t >> 6;
    int g = c_off >> 4, ui = c_off & 15;
    int u0 = r0 >> 2;
    int c  = g * 1024 + u0 + ui;
    int rl = 4 * ui + g;
    for (int i = 0; i < 16; i++) {
        int k = k0 + k_grp * 16 + i;
        float v = 0.f;
        if (k < 16)        v = kern[(size_t)k * NROWS + c];
        else if (k < 1040) v = rec[(size_t)(k - 16) * NROWS + c];
        tile[rl][k_grp * 16 + i] = (__bf16)v;
    }
    __syncthreads();
    int rl2 = t >> 2, ch = t & 3;
    bf16x8* dst = (bf16x8*)(Wcat + (size_t)(r0 + rl2) * KTOT + k0 + ch * 16);
    const bf16x8* src = (const bf16x8*)&tile[rl2][ch * 16];
    dst[0] = src[0];
    dst[1] = src[1];
}

// ---------------------------------------------------------------------------
// Zero Abuf buffers, write x[:,0,:] into Abuf0 cols 0..15, precompute
// tval[t][m] = x[m,t,0] and keepf[t][m] = any(x[m,t,:] != -1) ? 1 : 0.
// ---------------------------------------------------------------------------
__global__ __launch_bounds__(256) void prep_state(const float* __restrict__ x,
                                                  __bf16* __restrict__ Ab0,
                                                  __bf16* __restrict__ Ab1,
                                                  float* __restrict__ tval,
                                                  float* __restrict__ keepf) {
    int tid = blockIdx.x * 256 + threadIdx.x;
    int np  = gridDim.x * 256;
    const int AB = BATCH * KTOT;
    for (int i = tid; i < 2 * AB; i += np) {
        int which = (i < AB) ? 0 : 1;
        int p = i - which * AB;
        int col = p % KTOT;
        int m   = p / KTOT;
        __bf16 v = (__bf16)0.f;
        if (which == 0 && col < FEAT) v = (__bf16)x[(size_t)m * TSTEPS * FEAT + col];
        if (which == 0) Ab0[p] = v; else Ab1[p] = v;
    }
    for (int i = tid; i < TSTEPS * BATCH; i += np) {
        int t = i >> 8, m = i & 255;
        const float* row = x + (size_t)m * TSTEPS * FEAT + (size_t)t * FEAT;
        float tv = row[0];
        bool any = false;
#pragma unroll
        for (int f = 0; f < FEAT; f++) any = any || (row[f] != -1.0f);
        tval[i] = tv;
        keepf[i] = any ? 1.f : 0.f;
    }
}

// ---------------------------------------------------------------------------
// Persistent warm phase: 512 PLSTM steps in one cooperative launch.
// Grid 256 blocks (1/CU) x 256 thr. BM=32, BN=128, BK=64, double-buffered LDS.
// h/c state lives in registers for the whole loop; written to h32/c32 at end.
// ---------------------------------------------------------------------------
__global__ __launch_bounds__(256, 1) void warm_kernel(
    const __bf16* __restrict__ Wcat, __bf16* __restrict__ Ab0,
    __bf16* __restrict__ Ab1, float* __restrict__ h32, float* __restrict__ c32,
    const float* __restrict__ bias, const float* __restrict__ period,
    const float* __restrict__ phase, const float* __restrict__ ratio,
    const float* __restrict__ tval, const float* __restrict__ keepf,
    const float* __restrict__ x) {
    cg::grid_group grid = cg::this_grid();
    __shared__ __align__(16) __bf16 As[2][32][72];
    __shared__ __align__(16) __bf16 Bs[2][128][72];
    int b = blockIdx.x;
    int xcd = b & 7, ib = b >> 3;
    int n_block = xcd * 4 + (ib & 3);
    int m_block = ib >> 2;
    int m0 = m_block * 32;
    int n0 = n_block * 128;
    int tid = threadIdx.x;
    int lane = tid & 63, wave = tid >> 6;
    int l16 = lane & 15, quad = lane >> 4;
    int wn0 = wave * 32;
    int arow = tid >> 3;
    int ach  = (tid & 7) * 8;
    bool wlane = ((lane & 3) == 0);
    int ublk0 = n_block * 32;

    // preload per-lane unit constants (u set is fixed across all steps)
    int un[2];
    float bi[2], bfg[2], bgg[2], bog[2], pe[2], ph_[2], ro_[2];
#pragma unroll
    for (int nt = 0; nt < 2; nt++) {
        un[nt] = ublk0 + ((wn0 + nt * 16 + l16) >> 2);
        bi[nt]  = bias[un[nt]];
        bfg[nt] = bias[UNITS + un[nt]];
        bgg[nt] = bias[2 * UNITS + un[nt]];
        bog[nt] = bias[3 * UNITS + un[nt]];
        pe[nt]  = period[un[nt]];
        ph_[nt] = phase[un[nt]];
        ro_[nt] = ratio[un[nt]];
    }
    float hreg[2][8] = {{0.f}}, creg[2][8] = {{0.f}};

    const __bf16* bptr = Wcat + (size_t)(n0 + arow) * KTOT + ach;

#pragma unroll 1
    for (int t = 0; t < TSTEPS; t++) {
        const __bf16* Ar = (t & 1) ? Ab1 : Ab0;
        __bf16*       Aw = (t & 1) ? Ab0 : Ab1;
        const __bf16* aptr = Ar + (size_t)(m0 + arow) * KTOT + ach;

        // stage kt=0 into buffer 0
        *(bf16x8*)&As[0][arow][ach] = *(const bf16x8*)(aptr);
#pragma unroll
        for (int ii = 0; ii < 4; ii++)
            *(bf16x8*)&Bs[0][arow + ii * 32][ach] =
                *(const bf16x8*)(bptr + (size_t)ii * 32 * KTOT);

        f32x4 acc[2][2] = {};
#pragma unroll 1
        for (int kt = 0; kt < 17; kt++) {
            int cur = kt & 1;
            __syncthreads();
            if (kt < 16) {
                int kb = (kt + 1) * 64;
                *(bf16x8*)&As[cur ^ 1][arow][ach] = *(const bf16x8*)(aptr + kb);
#pragma unroll
                for (int ii = 0; ii < 4; ii++)
                    *(bf16x8*)&Bs[cur ^ 1][arow + ii * 32][ach] =
                        *(const bf16x8*)(bptr + (size_t)ii * 32 * KTOT + kb);
            }
#pragma unroll
            for (int s = 0; s < 2; s++) {
                bf16x8 a0 = *(const bf16x8*)&As[cur][l16][s * 32 + quad * 8];
                bf16x8 a1f = *(const bf16x8*)&As[cur][16 + l16][s * 32 + quad * 8];
                bf16x8 b0 = *(const bf16x8*)&Bs[cur][wn0 + l16][s * 32 + quad * 8];
                bf16x8 b1 = *(const bf16x8*)&Bs[cur][wn0 + 16 + l16][s * 32 + quad * 8];
                acc[0][0] = __builtin_amdgcn_mfma_f32_16x16x32_bf16(a0, b0, acc[0][0], 0, 0, 0);
                acc[0][1] = __builtin_amdgcn_mfma_f32_16x16x32_bf16(a0, b1, acc[0][1], 0, 0, 0);
                acc[1][0] = __builtin_amdgcn_mfma_f32_16x16x32_bf16(a1f, b0, acc[1][0], 0, 0, 0);
                acc[1][1] = __builtin_amdgcn_mfma_f32_16x16x32_bf16(a1f, b1, acc[1][1], 0, 0, 0);
            }
        }

        // epilogue: gate combine via DPP quad broadcast, state in registers
#pragma unroll
        for (int mt = 0; mt < 2; mt++) {
#pragma unroll
            for (int r = 0; r < 4; r++) {
                int mg = m0 + mt * 16 + quad * 4 + r;
                float tv = tval[t * BATCH + mg];
                bool keep = (keepf[t * BATCH + mg] == 0.f);
#pragma unroll
                for (int nt = 0; nt < 2; nt++) {
                    float z = acc[mt][nt][r];
                    float zi = qb<0x00>(z);
                    float zf = qb<0x55>(z);
                    float zg = qb<0xAA>(z);
                    float zo = qb<0xFF>(z);
                    if (wlane) {
                        int j = mt * 4 + r;
                        float ig = sigmoidf_(zi + bi[nt]);
                        float fg = sigmoidf_(zf + bfg[nt]);
                        float gv = tanhf_(zg + bgg[nt]);
                        float og = sigmoidf_(zo + bog[nt]);
                        float cp = creg[nt][j], hp = hreg[nt][j];
                        float nc = fg * cp + ig * gv;
                        float nh = og * tanhf_(nc);
                        float cr = fmodf(tv - ph_[nt], pe[nt]);
                        cr = (cr < 0.f) ? cr + pe[nt] : cr;
                        cr = cr / pe[nt];
                        float kup = 2.f * cr / ro_[nt];
                        float kk = (cr < ro_[nt]) ? (2.f - kup) : (0.001f * cr);
                        kk = (cr < 0.5f * ro_[nt]) ? kup : kk;
                        float ho = kk * nh + (1.f - kk) * hp;
                        float co = kk * nc + (1.f - kk) * cp;
                        if (keep) { ho = hp; co = cp; }
                        hreg[nt][j] = ho;
                        creg[nt][j] = co;
                        Aw[(size_t)mg * KTOT + 16 + un[nt]] = (__bf16)ho;
                    }
                }
            }
        }
        // stage next-step x into the write buffer
        if (t < TSTEPS - 1 && n_block == 0) {
            for (int idx = tid; idx < 32 * FEAT; idx += 256) {
                int row = idx >> 4, f = idx & 15;
                Aw[(size_t)(m0 + row) * KTOT + f] =
                    (__bf16)x[(size_t)(m0 + row) * (TSTEPS * FEAT) + (size_t)(t + 1) * FEAT + f];
            }
        }
        grid.sync();
    }

    // write final h/c state for the AR phase
    if (wlane) {
#pragma unroll
        for (int nt = 0; nt < 2; nt++) {
#pragma unroll
            for (int mt = 0; mt < 2; mt++) {
#pragma unroll
                for (int r = 0; r < 4; r++) {
                    int mg = m0 + mt * 16 + quad * 4 + r;
                    size_t off = (size_t)mg * UNITS + un[nt];
                    h32[off] = hreg[nt][mt * 4 + r];
                    c32[off] = creg[nt][mt * 4 + r];
                }
            }
        }
    }
}

// ---------------------------------------------------------------------------
// AR-phase PLSTM step (same as round-2 passing version).
// ---------------------------------------------------------------------------
__global__ __launch_bounds__(256) void step_kernel(
    const __bf16* __restrict__ Wcat, const __bf16* __restrict__ Abuf_r,
    __bf16* __restrict__ Abuf_w, float* __restrict__ h32, float* __restrict__ c32,
    const float* __restrict__ bias, const float* __restrict__ period,
    const float* __restrict__ phase, const float* __restrict__ ratio,
    const float* __restrict__ tsrc, int tstride) {
    __shared__ __align__(16) __bf16 As[32][72];
    __shared__ __align__(16) __bf16 Bs[128][72];
    int b = blockIdx.x;
    int xcd = b & 7, ib = b >> 3;
    int n_block = xcd * 4 + (ib & 3);
    int m_block = ib >> 2;
    int m0 = m_block * 32;
    int n0 = n_block * 128;
    int tid = threadIdx.x;
    int lane = tid & 63, wave = tid >> 6;
    int l16 = lane & 15, quad = lane >> 4;
    int wn0 = wave * 32;

    f32x4 acc[2][2] = {};
    int arow = tid >> 3;
    int ach  = (tid & 7) * 8;
    const __bf16* aptr = Abuf_r + (size_t)(m0 + arow) * KTOT + ach;
    const __bf16* bptr = Wcat + (size_t)(n0 + arow) * KTOT + ach;

    for (int kt = 0; kt < 17; kt++) {
        int kb = kt * 64;
        *(bf16x8*)&As[arow][ach] = *(const bf16x8*)(aptr + kb);
#pragma unroll
        for (int ii = 0; ii < 4; ii++) {
            *(bf16x8*)&Bs[arow + ii * 32][ach] =
                *(const bf16x8*)(bptr + (size_t)ii * 32 * KTOT + kb);
        }
        __syncthreads();
#pragma unroll
        for (int s = 0; s < 2; s++) {
            bf16x8 a0 = *(const bf16x8*)&As[l16][s * 32 + quad * 8];
            bf16x8 a1 = *(const bf16x8*)&As[16 + l16][s * 32 + quad * 8];
            bf16x8 b0 = *(const bf16x8*)&Bs[wn0 + l16][s * 32 + quad * 8];
            bf16x8 b1 = *(const bf16x8*)&Bs[wn0 + 16 + l16][s * 32 + quad * 8];
            acc[0][0] = __builtin_amdgcn_mfma_f32_16x16x32_bf16(a0, b0, acc[0][0], 0, 0, 0);
            acc[0][1] = __builtin_amdgcn_mfma_f32_16x16x32_bf16(a0, b1, acc[0][1], 0, 0, 0);
            acc[1][0] = __builtin_amdgcn_mfma_f32_16x16x32_bf16(a1, b0, acc[1][0], 0, 0, 0);
            acc[1][1] = __builtin_amdgcn_mfma_f32_16x16x32_bf16(a1, b1, acc[1][1], 0, 0, 0);
        }
        __syncthreads();
    }

    int ublk0 = n_block * 32;
    bool wlane = ((lane & 3) == 0);
#pragma unroll
    for (int mt = 0; mt < 2; mt++) {
#pragma unroll
        for (int r = 0; r < 4; r++) {
            int m_loc = mt * 16 + quad * 4 + r;
            int mg = m0 + m_loc;
            float tv = 0.f;
            if (wlane) tv = tsrc[(size_t)mg * tstride];
#pragma unroll
            for (int nt = 0; nt < 2; nt++) {
                float z = acc[mt][nt][r];
                float zi = qb<0x00>(z);
                float zf = qb<0x55>(z);
                float zg = qb<0xAA>(z);
                float zo = qb<0xFF>(z);
                if (wlane) {
                    int u = ublk0 + ((wn0 + nt * 16 + l16) >> 2);
                    zi += bias[u];
                    zf += bias[UNITS + u];
                    zg += bias[2 * UNITS + u];
                    zo += bias[3 * UNITS + u];
                    float ig = sigmoidf_(zi), fg = sigmoidf_(zf), og = sigmoidf_(zo);
                    float gv = tanhf_(zg);
                    size_t off = (size_t)mg * UNITS + u;
                    float cp = c32[off], hp = h32[off];
                    float nc = fg * cp + ig * gv;
                    float nh = og * tanhf_(nc);
                    float per = period[u], ph = phase[u], ro = ratio[u];
                    float cr = fmodf(tv - ph, per);
                    cr = (cr < 0.f) ? cr + per : cr;
                    cr = cr / per;
                    float kup = 2.f * cr / ro;
                    float kk = (cr < ro) ? (2.f - kup) : (0.001f * cr);
                    kk = (cr < 0.5f * ro) ? kup : kk;
                    float ho = kk * nh + (1.f - kk) * hp;
                    float co = kk * nc + (1.f - kk) * cp;
                    h32[off] = ho;
                    c32[off] = co;
                    Abuf_w[(size_t)mg * KTOT + 16 + u] = (__bf16)ho;
                }
            }
        }
    }
}

// ---------------------------------------------------------------------------
__global__ __launch_bounds__(256) void dense1(const float* __restrict__ h32,
                                              const float* __restrict__ w1,
                                              const float* __restrict__ b1,
                                              float* __restrict__ a1) {
    int m0 = blockIdx.x * 4;
    int j = threadIdx.x;
    float a0 = 0.f, a1v = 0.f, a2 = 0.f, a3 = 0.f;
    for (int k = 0; k < UNITS; k++) {
        float w = w1[(size_t)k * 256 + j];
        a0 += h32[(size_t)(m0 + 0) * UNITS + k] * w;
        a1v += h32[(size_t)(m0 + 1) * UNITS + k] * w;
        a2 += h32[(size_t)(m0 + 2) * UNITS + k] * w;
        a3 += h32[(size_t)(m0 + 3) * UNITS + k] * w;
    }
    float bb = b1[j];
    a1[(size_t)(m0 + 0) * 256 + j] = tanhf_(a0 + bb);
    a1[(size_t)(m0 + 1) * 256 + j] = tanhf_(a1v + bb);
    a1[(size_t)(m0 + 2) * 256 + j] = tanhf_(a2 + bb);
    a1[(size_t)(m0 + 3) * 256 + j] = tanhf_(a3 + bb);
}

// ---------------------------------------------------------------------------
__global__ __launch_bounds__(256) void dense_tail(
    const float* __restrict__ a1, const float* __restrict__ w2, const float* __restrict__ b2,
    const float* __restrict__ w3, const float* __restrict__ b3, const float* __restrict__ wo,
    const float* __restrict__ bo, float* __restrict__ out, __bf16* __restrict__ Abuf_x, int s) {
    __shared__ float a1s[8][256];
    __shared__ float a2s[8][128];
    __shared__ float a3s[8][64];
    int m0 = blockIdx.x * 8;
    int t = threadIdx.x;
    for (int i = 0; i < 8; i++) {
        int idx = t + i * 256;
        int r = idx >> 8, c = idx & 255;
        a1s[r][c] = a1[(size_t)(m0 + r) * 256 + c];
    }
    __syncthreads();
    {
        int j = t & 127, rb = t >> 7;
        float acc[4] = {0.f, 0.f, 0.f, 0.f};
        for (int k = 0; k < 256; k++) {
            float w = w2[(size_t)k * 128 + j];
#pragma unroll
            for (int q = 0; q < 4; q++) acc[q] += a1s[rb * 4 + q][k] * w;
        }
        float bb = b2[j];
#pragma unroll
        for (int q = 0; q < 4; q++) a2s[rb * 4 + q][j] = tanhf_(acc[q] + bb);
    }
    __syncthreads();
    {
        int j = t & 63, rb = t >> 6;
        float acc[2] = {0.f, 0.f};
        for (int k = 0; k < 128; k++) {
            float w = w3[(size_t)k * 64 + j];
#pragma unroll
            for (int q = 0; q < 2; q++) acc[q] += a2s[rb * 2 + q][k] * w;
        }
        float bb = b3[j];
#pragma unroll
        for (int q = 0; q < 2; q++) a3s[rb * 2 + q][j] = tanhf_(acc[q] + bb);
    }
    __syncthreads();
    if (t < 128) {
        int j = t & 15, r = t >> 4;
        float acc = 0.f;
        for (int k = 0; k < 64; k++) acc += a3s[r][k] * wo[(size_t)k * 16 + j];
        float v = acc + bo[j];
        out[(size_t)(m0 + r) * (OUTSTEPS * FEAT) + s * FEAT + j] = v;
        Abuf_x[(size_t)(m0 + r) * KTOT + j] = (__bf16)v;
    }
}

// ---------------------------------------------------------------------------
extern "C" void kernel_launch(void* const* d_in, const int* in_sizes, int n_in,
                              void* d_out, int out_size, void* d_ws, size_t ws_size,
                              hipStream_t stream) {
    const float* x      = (const float*)d_in[0];
    const float* kern   = (const float*)d_in[1];
    const float* rec    = (const float*)d_in[2];
    const float* bias   = (const float*)d_in[3];
    const float* period = (const float*)d_in[4];
    const float* phase  = (const float*)d_in[5];
    const float* ratio  = (const float*)d_in[6];
    const float* w1 = (const float*)d_in[7];
    const float* b1 = (const float*)d_in[8];
    const float* w2 = (const float*)d_in[9];
    const float* b2 = (const float*)d_in[10];
    const float* w3 = (const float*)d_in[11];
    const float* b3 = (const float*)d_in[12];
    const float* wo = (const float*)d_in[13];
    const float* bo = (const float*)d_in[14];
    float* out = (float*)d_out;

    char* ws = (char*)d_ws;
    const size_t WCAT_B = (size_t)NROWS * KTOT * 2;
    const size_t AB_B   = (size_t)BATCH * KTOT * 2;
    __bf16* Wcat = (__bf16*)ws;
    __bf16* Ab0  = (__bf16*)(ws + WCAT_B);
    __bf16* Ab1  = (__bf16*)(ws + WCAT_B + AB_B);
    float*  h32  = (float*)(ws + WCAT_B + 2 * AB_B);
    float*  c32  = h32 + (size_t)BATCH * UNITS;
    float*  a1   = c32 + (size_t)BATCH * UNITS;
    float*  tval = a1 + (size_t)BATCH * 256;
    float*  keepf = tval + (size_t)TSTEPS * BATCH;

    prep_weights<<<dim3(64, 17), 256, 0, stream>>>(kern, rec, Wcat);
    prep_state<<<512, 256, 0, stream>>>(x, Ab0, Ab1, tval, keepf);

    {
        void* wargs[] = {(void*)&Wcat, (void*)&Ab0, (void*)&Ab1, (void*)&h32,
                         (void*)&c32, (void*)&bias, (void*)&period, (void*)&phase,
                         (void*)&ratio, (void*)&tval, (void*)&keepf, (void*)&x};
        hipLaunchCooperativeKernel((const void*)warm_kernel, dim3(256), dim3(256),
                                   wargs, 0, stream);
    }

    int rp = 0;  // warm loop toggled parity 512 times -> AR starts reading Ab0
    for (int s = 0; s < OUTSTEPS; s++) {
        dense1<<<64, 256, 0, stream>>>(h32, w1, b1, a1);
        dense_tail<<<32, 256, 0, stream>>>(a1, w2, b2, w3, b3, wo, bo, out,
                                           rp ? Ab1 : Ab0, s);
        if (s < OUTSTEPS - 1) {
            const float* tsrc = out + (size_t)s * FEAT;
            step_kernel<<<256, 256, 0, stream>>>(Wcat, rp ? Ab1 : Ab0, rp ? Ab0 : Ab1,
                                                 h32, c32, bias, period, phase, ratio,
                                                 tsrc, OUTSTEPS * FEAT);
            rp ^= 1;
        }
    }
}

// Round 4
// 17712.280 us; speedup vs baseline: 1.4603x; 1.4603x over previous
//
#include <hip/hip_runtime.h>
#include <hip/hip_bf16.h>

#define UNITS 1024
#define FEAT  16
#define TSTEPS 512
#define OUTSTEPS 24
#define BATCH 256
#define KTOT  1088   // 16 (x) + 1024 (h) + 48 pad
#define NROWS 4096   // 4*UNITS, reordered r = 4*u + gate
#define SCOPE_AGENT __HIP_MEMORY_SCOPE_AGENT

typedef __bf16 bf16x8 __attribute__((ext_vector_type(8)));
typedef float  f32x4  __attribute__((ext_vector_type(4)));

__device__ __forceinline__ float sigmoidf_(float x) { return 1.f / (1.f + __expf(-x)); }
__device__ __forceinline__ float tanhf_(float x)    { return 1.f - 2.f / (__expf(2.f * x) + 1.f); }

template <int CTRL>
__device__ __forceinline__ float qb(float v) {
    int i = __builtin_amdgcn_mov_dpp(__float_as_int(v), CTRL, 0xF, 0xF, false);
    return __int_as_float(i);
}

__device__ __forceinline__ unsigned int pack_bf16(float a, float b) {
    __bf16 b0 = (__bf16)a, b1 = (__bf16)b;
    unsigned short s0, s1;
    __builtin_memcpy(&s0, &b0, 2);
    __builtin_memcpy(&s1, &b1, 2);
    return (unsigned int)s0 | ((unsigned int)s1 << 16);
}

// ---------------------------------------------------------------------------
// Build Wcat_T[r][k] (bf16, row-major, stride KTOT), r = 4*u + g.
// ---------------------------------------------------------------------------
__global__ __launch_bounds__(256) void prep_weights(const float* __restrict__ kern,
                                                    const float* __restrict__ rec,
                                                    __bf16* __restrict__ Wcat) {
    __shared__ __align__(16) __bf16 tile[64][72];
    int r0 = blockIdx.x * 64;
    int k0 = blockIdx.y * 64;
    int t  = threadIdx.x;
    int c_off = t & 63;
    int k_grp = t >> 6;
    int g = c_off >> 4, ui = c_off & 15;
    int u0 = r0 >> 2;
    int c  = g * 1024 + u0 + ui;
    int rl = 4 * ui + g;
    for (int i = 0; i < 16; i++) {
        int k = k0 + k_grp * 16 + i;
        float v = 0.f;
        if (k < 16)        v = kern[(size_t)k * NROWS + c];
        else if (k < 1040) v = rec[(size_t)(k - 16) * NROWS + c];
        tile[rl][k_grp * 16 + i] = (__bf16)v;
    }
    __syncthreads();
    int rl2 = t >> 2, ch = t & 3;
    bf16x8* dst = (bf16x8*)(Wcat + (size_t)(r0 + rl2) * KTOT + k0 + ch * 16);
    const bf16x8* src = (const bf16x8*)&tile[rl2][ch * 16];
    dst[0] = src[0];
    dst[1] = src[1];
}

// ---------------------------------------------------------------------------
// Zero Abuf buffers, write x[:,0,:] into Abuf0 cols 0..15, precompute tval /
// keepf tables, zero the barrier counters (agent-scope so warm sees them).
// ---------------------------------------------------------------------------
__global__ __launch_bounds__(256) void prep_state(const float* __restrict__ x,
                                                  __bf16* __restrict__ Ab0,
                                                  __bf16* __restrict__ Ab1,
                                                  float* __restrict__ tval,
                                                  float* __restrict__ keepf,
                                                  int* __restrict__ counters) {
    int tid = blockIdx.x * 256 + threadIdx.x;
    int np  = gridDim.x * 256;
    if (blockIdx.x == 0 && threadIdx.x < 4)
        __hip_atomic_store(counters + threadIdx.x * 64, 0, __ATOMIC_RELAXED, SCOPE_AGENT);
    const int AB = BATCH * KTOT;
    for (int i = tid; i < 2 * AB; i += np) {
        int which = (i < AB) ? 0 : 1;
        int p = i - which * AB;
        int col = p % KTOT;
        int m   = p / KTOT;
        __bf16 v = (__bf16)0.f;
        if (which == 0 && col < FEAT) v = (__bf16)x[(size_t)m * TSTEPS * FEAT + col];
        if (which == 0) Ab0[p] = v; else Ab1[p] = v;
    }
    for (int i = tid; i < TSTEPS * BATCH; i += np) {
        int t = i >> 8, m = i & 255;
        const float* row = x + (size_t)m * TSTEPS * FEAT + (size_t)t * FEAT;
        float tv = row[0];
        bool any = false;
#pragma unroll
        for (int f = 0; f < FEAT; f++) any = any || (row[f] != -1.0f);
        tval[i] = tv;
        keepf[i] = any ? 1.f : 0.f;
    }
}

// ---------------------------------------------------------------------------
// Persistent warm kernel. 256 blocks (co-resident, cooperative). Block
// (mi,ni): BM=64 batch rows [mi*64..), BN=64 gate-rows [ni*64..).
// B-slice lives in LDS (frag-major) for all 512 steps; h/c in registers.
// Cross-block h exchange: sc1 atomic stores -> LLC; per-mi-group (64 blocks)
// monotonic counter barrier; acquire fence invalidates stale L2 lines.
// ---------------------------------------------------------------------------
#define BS_FRAGS (34 * 4)           // (ks 0..33) x (nng 0..3), 1KB each
#define SMEM_BYTES ((BS_FRAGS * 512 + 2 * 8 * 512) * 2)   // 155648

__global__ __launch_bounds__(256, 1) void warm_kernel(
    const __bf16* __restrict__ Wcat, __bf16* __restrict__ Ab0,
    __bf16* __restrict__ Ab1, float* __restrict__ h32, float* __restrict__ c32,
    const float* __restrict__ bias, const float* __restrict__ period,
    const float* __restrict__ phase, const float* __restrict__ ratio,
    const float* __restrict__ tval, const float* __restrict__ keepf,
    const float* __restrict__ x, int* __restrict__ counters) {
    extern __shared__ __align__(16) char smem[];
    __bf16* Bs = (__bf16*)smem;                                // 136 frags
    __bf16* As = (__bf16*)(smem + BS_FRAGS * 512 * 2);         // 2 bufs x 8 frags

    int b = blockIdx.x;
    int mi = (b >> 1) & 3;                 // mi-group on XCD pair {2mi,2mi+1}
    int ni = ((b >> 3) << 1) | (b & 1);    // 0..63
    int m0 = mi * 64;
    int tid = threadIdx.x;
    int lane = tid & 63, w = tid >> 6;
    int l16 = lane & 15, quad = lane >> 4;
    int wq_m = w & 1, wq_n = w >> 1;
    int* cnt = counters + mi * 64;
    bool wlane = ((l16 & 3) == 0);

    // ---- stage B slice into LDS, fragment-major (done once) ----
    for (int C = tid; C < BS_FRAGS * 64; C += 256) {
        int frag = C >> 6, pos = C & 63;
        int ksg = frag >> 2, nng = frag & 3;
        int row = ni * 64 + nng * 16 + (pos & 15);
        int col = ksg * 32 + (pos >> 4) * 8;
        *(bf16x8*)&Bs[(size_t)C * 8] = *(const bf16x8*)(Wcat + (size_t)row * KTOT + col);
    }
    // per-lane unit constants
    int un[2]; float bi[2], bf_[2], bg_[2], bo_[2], pe[2], ph_[2], ro_[2];
#pragma unroll
    for (int nn = 0; nn < 2; nn++) {
        un[nn] = ni * 16 + wq_n * 8 + nn * 4 + (l16 >> 2);
        bi[nn] = bias[un[nn]];
        bf_[nn] = bias[UNITS + un[nn]];
        bg_[nn] = bias[2 * UNITS + un[nn]];
        bo_[nn] = bias[3 * UNITS + un[nn]];
        pe[nn] = period[un[nn]];
        ph_[nn] = phase[un[nn]];
        ro_[nn] = ratio[un[nn]];
    }
    float hreg[2][8] = {{0.f}}, creg[2][8] = {{0.f}};
    __syncthreads();

#pragma unroll 1
    for (int t = 0; t < TSTEPS; t++) {
        if (t > 0) {
            int target = 64 * t;
            while (__hip_atomic_load(cnt, __ATOMIC_RELAXED, SCOPE_AGENT) < target)
                __builtin_amdgcn_s_sleep(1);
            __builtin_amdgcn_fence(__ATOMIC_ACQUIRE, "agent");
        }
        const __bf16* Ar = (t & 1) ? Ab1 : Ab0;
        __bf16*       Aw = (t & 1) ? Ab0 : Ab1;

        // prefetch epilogue scalars (latency hidden by K-loop)
        float tv[2][4], kf[2][4];
#pragma unroll
        for (int mm = 0; mm < 2; mm++)
#pragma unroll
            for (int r = 0; r < 4; r++) {
                int mg = m0 + wq_m * 32 + mm * 16 + quad * 4 + r;
                tv[mm][r] = tval[t * BATCH + mg];
                kf[mm][r] = keepf[t * BATCH + mg];
            }

        // A staging: wave w stages m-rows [w*16, +16); lane l -> frag pos l.
        const __bf16* arow = Ar + (size_t)(m0 + w * 16 + l16) * KTOT + quad * 8;
        bf16x8 r0 = *(const bf16x8*)(arow);
        bf16x8 r1 = *(const bf16x8*)(arow + 32);
        f32x4 acc[2][2] = {};

#pragma unroll 1
        for (int kt = 0; kt < 17; kt++) {
            int buf = kt & 1;
            __bf16* Ad = As + ((size_t)(buf * 8 + w) * 64 + lane) * 8;
            *(bf16x8*)Ad = r0;                       // frag (ksl=0, mmg=w)
            *(bf16x8*)(Ad + 4 * 64 * 8) = r1;        // frag (ksl=1, mmg=w)
            __syncthreads();
            if (kt < 16) {
                int kb = (kt + 1) * 64;
                r0 = *(const bf16x8*)(arow + kb);
                r1 = *(const bf16x8*)(arow + kb + 32);
            }
#pragma unroll
            for (int ks = 0; ks < 2; ks++) {
                bf16x8 a0 = *(const bf16x8*)&As[((size_t)(buf * 8 + ks * 4 + wq_m * 2 + 0) * 64 + lane) * 8];
                bf16x8 a1 = *(const bf16x8*)&As[((size_t)(buf * 8 + ks * 4 + wq_m * 2 + 1) * 64 + lane) * 8];
                bf16x8 b0 = *(const bf16x8*)&Bs[((size_t)((kt * 2 + ks) * 4 + wq_n * 2 + 0) * 64 + lane) * 8];
                bf16x8 b1 = *(const bf16x8*)&Bs[((size_t)((kt * 2 + ks) * 4 + wq_n * 2 + 1) * 64 + lane) * 8];
                acc[0][0] = __builtin_amdgcn_mfma_f32_16x16x32_bf16(a0, b0, acc[0][0], 0, 0, 0);
                acc[0][1] = __builtin_amdgcn_mfma_f32_16x16x32_bf16(a0, b1, acc[0][1], 0, 0, 0);
                acc[1][0] = __builtin_amdgcn_mfma_f32_16x16x32_bf16(a1, b0, acc[1][0], 0, 0, 0);
                acc[1][1] = __builtin_amdgcn_mfma_f32_16x16x32_bf16(a1, b1, acc[1][1], 0, 0, 0);
            }
        }

        // epilogue: gates via DPP quad broadcast; state in regs; h -> Aw (sc1)
#pragma unroll
        for (int mm = 0; mm < 2; mm++)
#pragma unroll
            for (int r = 0; r < 4; r++) {
                int mg = m0 + wq_m * 32 + mm * 16 + quad * 4 + r;
#pragma unroll
                for (int nn = 0; nn < 2; nn++) {
                    float z = acc[mm][nn][r];
                    float zi = qb<0x00>(z);
                    float zf = qb<0x55>(z);
                    float zg = qb<0xAA>(z);
                    float zo = qb<0xFF>(z);
                    float ho = 0.f, co = 0.f;
                    if (wlane) {
                        int j = mm * 4 + r;
                        float ig = sigmoidf_(zi + bi[nn]);
                        float fg = sigmoidf_(zf + bf_[nn]);
                        float gv = tanhf_(zg + bg_[nn]);
                        float og = sigmoidf_(zo + bo_[nn]);
                        float cp = creg[nn][j], hp = hreg[nn][j];
                        float nc = fg * cp + ig * gv;
                        float nh = og * tanhf_(nc);
                        float cr = fmodf(tv[mm][r] - ph_[nn], pe[nn]);
                        cr = (cr < 0.f) ? cr + pe[nn] : cr;
                        cr = cr / pe[nn];
                        float kup = 2.f * cr / ro_[nn];
                        float kk = (cr < ro_[nn]) ? (2.f - kup) : (0.001f * cr);
                        kk = (cr < 0.5f * ro_[nn]) ? kup : kk;
                        ho = kk * nh + (1.f - kk) * hp;
                        co = kk * nc + (1.f - kk) * cp;
                        if (kf[mm][r] == 0.f) { ho = hp; co = cp; }
                        hreg[nn][j] = ho;
                        creg[nn][j] = co;
                    }
                    float hn = __shfl(ho, lane + 4);   // partner holds u+1
                    if (wlane && ((l16 & 7) == 0)) {
                        unsigned int pk = pack_bf16(ho, hn);
                        unsigned int* dst = (unsigned int*)(Aw + (size_t)mg * KTOT + 16 + un[nn]);
                        __hip_atomic_store(dst, pk, __ATOMIC_RELAXED, SCOPE_AGENT);
                    }
                }
            }
        // stage next-step x (cols 0..15) — ni==0 blocks only
        if (ni == 0 && t < TSTEPS - 1) {
#pragma unroll
            for (int j = tid; j < 512; j += 256) {
                int row = j >> 3, fp = (j & 7) * 2;
                const float* src = x + (size_t)(m0 + row) * (TSTEPS * FEAT) + (size_t)(t + 1) * FEAT + fp;
                unsigned int pk = pack_bf16(src[0], src[1]);
                unsigned int* dst = (unsigned int*)(Aw + (size_t)(m0 + row) * KTOT) + (fp >> 1);
                __hip_atomic_store(dst, pk, __ATOMIC_RELAXED, SCOPE_AGENT);
            }
        }
        __syncthreads();   // drains all waves' vmem stores before the add
        if (tid == 0)
            __hip_atomic_fetch_add(cnt, 1, __ATOMIC_RELEASE, SCOPE_AGENT);
    }

    // final h/c state for the AR phase (normal stores; boundary flush covers)
    if (wlane) {
#pragma unroll
        for (int nn = 0; nn < 2; nn++)
#pragma unroll
            for (int mm = 0; mm < 2; mm++)
#pragma unroll
                for (int r = 0; r < 4; r++) {
                    int mg = m0 + wq_m * 32 + mm * 16 + quad * 4 + r;
                    size_t off = (size_t)mg * UNITS + un[nn];
                    h32[off] = hreg[nn][mm * 4 + r];
                    c32[off] = creg[nn][mm * 4 + r];
                }
    }
}

// ---------------------------------------------------------------------------
// AR-phase PLSTM step (round-2/3 proven version).
// ---------------------------------------------------------------------------
__global__ __launch_bounds__(256) void step_kernel(
    const __bf16* __restrict__ Wcat, const __bf16* __restrict__ Abuf_r,
    __bf16* __restrict__ Abuf_w, float* __restrict__ h32, float* __restrict__ c32,
    const float* __restrict__ bias, const float* __restrict__ period,
    const float* __restrict__ phase, const float* __restrict__ ratio,
    const float* __restrict__ tsrc, int tstride) {
    __shared__ __align__(16) __bf16 As[32][72];
    __shared__ __align__(16) __bf16 Bs[128][72];
    int b = blockIdx.x;
    int xcd = b & 7, ib = b >> 3;
    int n_block = xcd * 4 + (ib & 3);
    int m_block = ib >> 2;
    int m0 = m_block * 32;
    int n0 = n_block * 128;
    int tid = threadIdx.x;
    int lane = tid & 63, wave = tid >> 6;
    int l16 = lane & 15, quad = lane >> 4;
    int wn0 = wave * 32;

    f32x4 acc[2][2] = {};
    int arow = tid >> 3;
    int ach  = (tid & 7) * 8;
    const __bf16* aptr = Abuf_r + (size_t)(m0 + arow) * KTOT + ach;
    const __bf16* bptr = Wcat + (size_t)(n0 + arow) * KTOT + ach;

    for (int kt = 0; kt < 17; kt++) {
        int kb = kt * 64;
        *(bf16x8*)&As[arow][ach] = *(const bf16x8*)(aptr + kb);
#pragma unroll
        for (int ii = 0; ii < 4; ii++) {
            *(bf16x8*)&Bs[arow + ii * 32][ach] =
                *(const bf16x8*)(bptr + (size_t)ii * 32 * KTOT + kb);
        }
        __syncthreads();
#pragma unroll
        for (int s = 0; s < 2; s++) {
            bf16x8 a0 = *(const bf16x8*)&As[l16][s * 32 + quad * 8];
            bf16x8 a1 = *(const bf16x8*)&As[16 + l16][s * 32 + quad * 8];
            bf16x8 b0 = *(const bf16x8*)&Bs[wn0 + l16][s * 32 + quad * 8];
            bf16x8 b1 = *(const bf16x8*)&Bs[wn0 + 16 + l16][s * 32 + quad * 8];
            acc[0][0] = __builtin_amdgcn_mfma_f32_16x16x32_bf16(a0, b0, acc[0][0], 0, 0, 0);
            acc[0][1] = __builtin_amdgcn_mfma_f32_16x16x32_bf16(a0, b1, acc[0][1], 0, 0, 0);
            acc[1][0] = __builtin_amdgcn_mfma_f32_16x16x32_bf16(a1, b0, acc[1][0], 0, 0, 0);
            acc[1][1] = __builtin_amdgcn_mfma_f32_16x16x32_bf16(a1, b1, acc[1][1], 0, 0, 0);
        }
        __syncthreads();
    }

    int ublk0 = n_block * 32;
    bool wlane = ((lane & 3) == 0);
#pragma unroll
    for (int mt = 0; mt < 2; mt++) {
#pragma unroll
        for (int r = 0; r < 4; r++) {
            int m_loc = mt * 16 + quad * 4 + r;
            int mg = m0 + m_loc;
            float tvv = 0.f;
            if (wlane) tvv = tsrc[(size_t)mg * tstride];
#pragma unroll
            for (int nt = 0; nt < 2; nt++) {
                float z = acc[mt][nt][r];
                float zi = qb<0x00>(z);
                float zf = qb<0x55>(z);
                float zg = qb<0xAA>(z);
                float zo = qb<0xFF>(z);
                if (wlane) {
                    int u = ublk0 + ((wn0 + nt * 16 + l16) >> 2);
                    zi += bias[u];
                    zf += bias[UNITS + u];
                    zg += bias[2 * UNITS + u];
                    zo += bias[3 * UNITS + u];
                    float ig = sigmoidf_(zi), fg = sigmoidf_(zf), og = sigmoidf_(zo);
                    float gv = tanhf_(zg);
                    size_t off = (size_t)mg * UNITS + u;
                    float cp = c32[off], hp = h32[off];
                    float nc = fg * cp + ig * gv;
                    float nh = og * tanhf_(nc);
                    float per = period[u], ph = phase[u], ro = ratio[u];
                    float cr = fmodf(tvv - ph, per);
                    cr = (cr < 0.f) ? cr + per : cr;
                    cr = cr / per;
                    float kup = 2.f * cr / ro;
                    float kk = (cr < ro) ? (2.f - kup) : (0.001f * cr);
                    kk = (cr < 0.5f * ro) ? kup : kk;
                    float ho = kk * nh + (1.f - kk) * hp;
                    float co = kk * nc + (1.f - kk) * cp;
                    h32[off] = ho;
                    c32[off] = co;
                    Abuf_w[(size_t)mg * KTOT + 16 + u] = (__bf16)ho;
                }
            }
        }
    }
}

// ---------------------------------------------------------------------------
__global__ __launch_bounds__(256) void dense1(const float* __restrict__ h32,
                                              const float* __restrict__ w1,
                                              const float* __restrict__ b1,
                                              float* __restrict__ a1) {
    int m0 = blockIdx.x * 4;
    int j = threadIdx.x;
    float a0 = 0.f, a1v = 0.f, a2 = 0.f, a3 = 0.f;
    for (int k = 0; k < UNITS; k++) {
        float w = w1[(size_t)k * 256 + j];
        a0 += h32[(size_t)(m0 + 0) * UNITS + k] * w;
        a1v += h32[(size_t)(m0 + 1) * UNITS + k] * w;
        a2 += h32[(size_t)(m0 + 2) * UNITS + k] * w;
        a3 += h32[(size_t)(m0 + 3) * UNITS + k] * w;
    }
    float bb = b1[j];
    a1[(size_t)(m0 + 0) * 256 + j] = tanhf_(a0 + bb);
    a1[(size_t)(m0 + 1) * 256 + j] = tanhf_(a1v + bb);
    a1[(size_t)(m0 + 2) * 256 + j] = tanhf_(a2 + bb);
    a1[(size_t)(m0 + 3) * 256 + j] = tanhf_(a3 + bb);
}

// ---------------------------------------------------------------------------
__global__ __launch_bounds__(256) void dense_tail(
    const float* __restrict__ a1, const float* __restrict__ w2, const float* __restrict__ b2,
    const float* __restrict__ w3, const float* __restrict__ b3, const float* __restrict__ wo,
    const float* __restrict__ bo, float* __restrict__ out, __bf16* __restrict__ Abuf_x, int s) {
    __shared__ float a1s[8][256];
    __shared__ float a2s[8][128];
    __shared__ float a3s[8][64];
    int m0 = blockIdx.x * 8;
    int t = threadIdx.x;
    for (int i = 0; i < 8; i++) {
        int idx = t + i * 256;
        int r = idx >> 8, c = idx & 255;
        a1s[r][c] = a1[(size_t)(m0 + r) * 256 + c];
    }
    __syncthreads();
    {
        int j = t & 127, rb = t >> 7;
        float acc[4] = {0.f, 0.f, 0.f, 0.f};
        for (int k = 0; k < 256; k++) {
            float w = w2[(size_t)k * 128 + j];
#pragma unroll
            for (int q = 0; q < 4; q++) acc[q] += a1s[rb * 4 + q][k] * w;
        }
        float bb = b2[j];
#pragma unroll
        for (int q = 0; q < 4; q++) a2s[rb * 4 + q][j] = tanhf_(acc[q] + bb);
    }
    __syncthreads();
    {
        int j = t & 63, rb = t >> 6;
        float acc[2] = {0.f, 0.f};
        for (int k = 0; k < 128; k++) {
            float w = w3[(size_t)k * 64 + j];
#pragma unroll
            for (int q = 0; q < 2; q++) acc[q] += a2s[rb * 2 + q][k] * w;
        }
        float bb = b3[j];
#pragma unroll
        for (int q = 0; q < 2; q++) a3s[rb * 2 + q][j] = tanhf_(acc[q] + bb);
    }
    __syncthreads();
    if (t < 128) {
        int j = t & 15, r = t >> 4;
        float acc = 0.f;
        for (int k = 0; k < 64; k++) acc += a3s[r][k] * wo[(size_t)k * 16 + j];
        float v = acc + bo[j];
        out[(size_t)(m0 + r) * (OUTSTEPS * FEAT) + s * FEAT + j] = v;
        Abuf_x[(size_t)(m0 + r) * KTOT + j] = (__bf16)v;
    }
}

// ---------------------------------------------------------------------------
extern "C" void kernel_launch(void* const* d_in, const int* in_sizes, int n_in,
                              void* d_out, int out_size, void* d_ws, size_t ws_size,
                              hipStream_t stream) {
    const float* x      = (const float*)d_in[0];
    const float* kern   = (const float*)d_in[1];
    const float* rec    = (const float*)d_in[2];
    const float* bias   = (const float*)d_in[3];
    const float* period = (const float*)d_in[4];
    const float* phase  = (const float*)d_in[5];
    const float* ratio  = (const float*)d_in[6];
    const float* w1 = (const float*)d_in[7];
    const float* b1 = (const float*)d_in[8];
    const float* w2 = (const float*)d_in[9];
    const float* b2 = (const float*)d_in[10];
    const float* w3 = (const float*)d_in[11];
    const float* b3 = (const float*)d_in[12];
    const float* wo = (const float*)d_in[13];
    const float* bo = (const float*)d_in[14];
    float* out = (float*)d_out;

    char* ws = (char*)d_ws;
    const size_t WCAT_B = (size_t)NROWS * KTOT * 2;
    const size_t AB_B   = (size_t)BATCH * KTOT * 2;
    __bf16* Wcat = (__bf16*)ws;
    __bf16* Ab0  = (__bf16*)(ws + WCAT_B);
    __bf16* Ab1  = (__bf16*)(ws + WCAT_B + AB_B);
    float*  h32  = (float*)(ws + WCAT_B + 2 * AB_B);
    float*  c32  = h32 + (size_t)BATCH * UNITS;
    float*  a1   = c32 + (size_t)BATCH * UNITS;
    float*  tval = a1 + (size_t)BATCH * 256;
    float*  keepf = tval + (size_t)TSTEPS * BATCH;
    int*    counters = (int*)(keepf + (size_t)TSTEPS * BATCH);

    static int smem_set = 0;
    if (!smem_set) {
        hipFuncSetAttribute((const void*)warm_kernel,
                            hipFuncAttributeMaxDynamicSharedMemorySize, SMEM_BYTES);
        smem_set = 1;
    }

    prep_weights<<<dim3(64, 17), 256, 0, stream>>>(kern, rec, Wcat);
    prep_state<<<512, 256, 0, stream>>>(x, Ab0, Ab1, tval, keepf, counters);

    {
        void* wargs[] = {(void*)&Wcat, (void*)&Ab0, (void*)&Ab1, (void*)&h32,
                         (void*)&c32, (void*)&bias, (void*)&period, (void*)&phase,
                         (void*)&ratio, (void*)&tval, (void*)&keepf, (void*)&x,
                         (void*)&counters};
        hipLaunchCooperativeKernel((const void*)warm_kernel, dim3(256), dim3(256),
                                   wargs, SMEM_BYTES, stream);
    }

    int rp = 0;  // warm toggled parity 512 times -> AR starts reading Ab0
    for (int s = 0; s < OUTSTEPS; s++) {
        dense1<<<64, 256, 0, stream>>>(h32, w1, b1, a1);
        dense_tail<<<32, 256, 0, stream>>>(a1, w2, b2, w3, b3, wo, bo, out,
                                           rp ? Ab1 : Ab0, s);
        if (s < OUTSTEPS - 1) {
            const float* tsrc = out + (size_t)s * FEAT;
            step_kernel<<<256, 256, 0, stream>>>(Wcat, rp ? Ab1 : Ab0, rp ? Ab0 : Ab1,
                                                 h32, c32, bias, period, phase, ratio,
                                                 tsrc, OUTSTEPS * FEAT);
            rp ^= 1;
        }
    }
}